// Round 2
// baseline (23568.320 us; speedup 1.0000x reference)
//
#include <hip/hip_runtime.h>
#include <math.h>

typedef short short8 __attribute__((ext_vector_type(8)));
typedef float f32x4 __attribute__((ext_vector_type(4)));

#define DT 0.042f
#define LSEQ 512
#define NI 96
#define NH 1024

__device__ __forceinline__ unsigned short f2bf(float f) {
  unsigned int u = __builtin_bit_cast(unsigned int, f);
  return (unsigned short)((u + 0x7fffu + ((u >> 16) & 1u)) >> 16);
}
__device__ __forceinline__ float bf2f(unsigned short h) {
  unsigned int u = ((unsigned int)h) << 16;
  return __builtin_bit_cast(float, u);
}

// 256 blocks x 256 threads, plain launch (all co-resident: 1 block/CU on 256 CUs).
// Block = (group g = bid&15 -> 8 batch rows) x (col-block jb = bid>>4 -> 64 cols).
// h2h/x2h column-slices live in VGPRs (hi+lo bf16) for all 512 steps.
// Per step: x-proj MFMAs (peer-independent) -> spin on 16 group flags -> h2h MFMAs
// from hi/lo bf16 exchange buffer -> fp32 state update -> publish hy hi/lo + fp32 out.
__global__ __launch_bounds__(256, 1) void ron_kernel(
    const float* __restrict__ x, const float* __restrict__ x2h,
    const float* __restrict__ h2h, const float* __restrict__ bias,
    const float* __restrict__ gam_, const float* __restrict__ eps_,
    float* __restrict__ out, unsigned int* __restrict__ flags,
    unsigned short* __restrict__ hy_ex) {
  const int tid = threadIdx.x;
  const int w = tid >> 6;
  const int l = tid & 63;
  const int g = blockIdx.x & 15;   // batch group (16 blocks/group)
  const int jb = blockIdx.x >> 4;  // column block
  const int col = jb * 64 + w * 16 + (l & 15);
  const int arow = l & 7;          // A-row (lanes 8-15 duplicate rows 0-7; C rows 8-15 dup'd, discarded)
  const int kg = l >> 4;           // k-group within fragment
  const int rbase = kg * 4;        // C-row base (col=lane&15, row=(lane>>4)*4+reg)

  // ---- one-time: weights -> hi/lo bf16 fragments in registers ----
  short8 wfh[32], wfl[32];
#pragma unroll
  for (int kt = 0; kt < 32; ++kt) {
#pragma unroll
    for (int jj = 0; jj < 8; ++jj) {
      float v = h2h[(size_t)(kt * 32 + kg * 8 + jj) * NH + col];
      unsigned short hb = f2bf(v);
      wfh[kt][jj] = (short)hb;
      wfl[kt][jj] = (short)f2bf(v - bf2f(hb));
    }
  }
  short8 xwh[3], xwl[3];
#pragma unroll
  for (int kt = 0; kt < 3; ++kt) {
#pragma unroll
    for (int jj = 0; jj < 8; ++jj) {
      float v = x2h[(size_t)(kt * 32 + kg * 8 + jj) * NH + col];
      unsigned short hb = f2bf(v);
      xwh[kt][jj] = (short)hb;
      xwl[kt][jj] = (short)f2bf(v - bf2f(hb));
    }
  }

  const float bias_c = bias[col];
  const float gam = gam_[col];
  const float ep = eps_[col];

  float hy[4] = {0.f, 0.f, 0.f, 0.f};
  float hz[4] = {0.f, 0.f, 0.f, 0.f};

  const float* xlane = x + (size_t)(g * 8 + arow) * LSEQ * NI + kg * 8;

  unsigned int* myflag = flags + (size_t)(g * 16 + jb) * 16;       // 64B-spaced
  unsigned int* watch = flags + (size_t)(g * 16 + (l & 15)) * 16;  // lane l watches producer l&15

  for (int s = 0; s < LSEQ; ++s) {
    f32x4 acc[4];
#pragma unroll
    for (int i = 0; i < 4; ++i) acc[i] = (f32x4){0.f, 0.f, 0.f, 0.f};

    // ---- fused x @ x2h (hi/lo split), peer-independent: issue BEFORE the spin ----
    const float* xs = xlane + (size_t)s * NI;
#pragma unroll
    for (int kt = 0; kt < 3; ++kt) {
      f32x4 x0 = *(const f32x4*)(xs + kt * 32);
      f32x4 x1 = *(const f32x4*)(xs + kt * 32 + 4);
      short8 axh, axl;
#pragma unroll
      for (int jj = 0; jj < 4; ++jj) {
        unsigned short hb = f2bf(x0[jj]);
        axh[jj] = (short)hb;
        axl[jj] = (short)f2bf(x0[jj] - bf2f(hb));
        unsigned short hb2 = f2bf(x1[jj]);
        axh[jj + 4] = (short)hb2;
        axl[jj + 4] = (short)f2bf(x1[jj] - bf2f(hb2));
      }
      acc[(3 * kt + 0) & 3] = __builtin_amdgcn_mfma_f32_16x16x32_bf16(axh, xwh[kt], acc[(3 * kt + 0) & 3], 0, 0, 0);
      acc[(3 * kt + 1) & 3] = __builtin_amdgcn_mfma_f32_16x16x32_bf16(axl, xwh[kt], acc[(3 * kt + 1) & 3], 0, 0, 0);
      acc[(3 * kt + 2) & 3] = __builtin_amdgcn_mfma_f32_16x16x32_bf16(axh, xwl[kt], acc[(3 * kt + 2) & 3], 0, 0, 0);
    }

    if (s) {
      // wait for all 16 producers of this group to have published step s-1
      int guard = 0;
      for (;;) {
        unsigned int v = __hip_atomic_load(watch, __ATOMIC_RELAXED, __HIP_MEMORY_SCOPE_AGENT);
        if (!__any((int)v < s)) break;
        if (++guard > (1 << 20)) break;  // anti-hang safety
        __builtin_amdgcn_s_sleep(1);
      }
      __threadfence();  // acquire

      const unsigned short* srch = hy_ex + (size_t)(((s & 1) ^ 1) * 16 + g) * 16384;
      const unsigned short* srcl = srch + 8192;
      const unsigned short* ah = srch + arow * NH + kg * 8;
      const unsigned short* al = srcl + arow * NH + kg * 8;
#pragma unroll
      for (int kt = 0; kt < 32; ++kt) {
        short8 fh = *(const short8*)(ah + kt * 32);
        short8 fl = *(const short8*)(al + kt * 32);
        const int b = 3 * kt + 1;
        acc[(b + 0) & 3] = __builtin_amdgcn_mfma_f32_16x16x32_bf16(fh, wfh[kt], acc[(b + 0) & 3], 0, 0, 0);
        acc[(b + 1) & 3] = __builtin_amdgcn_mfma_f32_16x16x32_bf16(fl, wfh[kt], acc[(b + 1) & 3], 0, 0, 0);
        acc[(b + 2) & 3] = __builtin_amdgcn_mfma_f32_16x16x32_bf16(fh, wfl[kt], acc[(b + 2) & 3], 0, 0, 0);
      }
    }

    f32x4 r = (acc[0] + acc[1]) + (acc[2] + acc[3]);

    // ---- fp32 state update in registers ----
#pragma unroll
    for (int i = 0; i < 4; ++i) {
      float a = r[i] + bias_c;
      float th = tanhf(a);
      hz[i] += DT * (th - gam * hy[i] - ep * hz[i]);
      hy[i] += DT * hz[i];
    }

    // ---- publish hy (hi/lo bf16, pair-packed) + fp32 output ----
    unsigned short* dsth = hy_ex + (size_t)((s & 1) * 16 + g) * 16384;
    unsigned short* dstl = dsth + 8192;
#pragma unroll
    for (int i = 0; i < 4; ++i) {
      unsigned short hb = f2bf(hy[i]);
      unsigned short lb = f2bf(hy[i] - bf2f(hb));
      unsigned int oh = (unsigned int)__shfl_xor((int)hb, 1, 64);
      unsigned int ol = (unsigned int)__shfl_xor((int)lb, 1, 64);
      if (l < 32) {
        if (!(l & 1)) {
          *(unsigned int*)(dsth + (rbase + i) * NH + col) = (unsigned int)hb | (oh << 16);
          *(unsigned int*)(dstl + (rbase + i) * NH + col) = (unsigned int)lb | (ol << 16);
        }
        out[((size_t)(g * 8 + rbase + i) * LSEQ + s) * NH + col] = hy[i];
      }
    }

    __threadfence();  // release: hy_ex visible agent-wide before flag
    __syncthreads();  // all 4 waves of this block done
    if (tid == 0)
      __hip_atomic_store(myflag, (unsigned int)(s + 1), __ATOMIC_RELAXED, __HIP_MEMORY_SCOPE_AGENT);
  }
}

extern "C" void kernel_launch(void* const* d_in, const int* in_sizes, int n_in,
                              void* d_out, int out_size, void* d_ws, size_t ws_size,
                              hipStream_t stream) {
  const float* x = (const float*)d_in[0];
  const float* x2h = (const float*)d_in[1];
  const float* h2h = (const float*)d_in[2];
  const float* bias = (const float*)d_in[3];
  const float* gam = (const float*)d_in[4];
  const float* eps = (const float*)d_in[5];
  float* out = (float*)d_out;

  unsigned int* flags = (unsigned int*)d_ws;                       // 16KB: 256 flags, 64B apart
  unsigned short* hy_ex = (unsigned short*)((char*)d_ws + 16384);  // 2 bufs x 16 g x (hi|lo 8192 shorts) = 1MB

  // only flags need zeroing (step 0 skips the h2h matmul -> exchange buffer never read uninitialized)
  hipMemsetAsync(d_ws, 0, 16384, stream);

  ron_kernel<<<dim3(256), dim3(256), 0, stream>>>(x, x2h, h2h, bias, gam, eps, out, flags, hy_ex);
}

// Round 3
// 2959.316 us; speedup vs baseline: 7.9641x; 7.9641x over previous
//
#include <hip/hip_runtime.h>
#include <math.h>

typedef short short8 __attribute__((ext_vector_type(8)));
typedef float f32x4 __attribute__((ext_vector_type(4)));
typedef unsigned long long u64;
typedef u64 u64x2 __attribute__((ext_vector_type(2)));

#define DT 0.042f
#define LSEQ 512
#define NI 96
#define NH 1024

static __device__ __forceinline__ unsigned short f2bf(float f) {
  unsigned int u = __builtin_bit_cast(unsigned int, f);
  return (unsigned short)((u + 0x7fffu + ((u >> 16) & 1u)) >> 16);
}
static __device__ __forceinline__ float bf2f(unsigned short h) {
  unsigned int u = ((unsigned int)h) << 16;
  return __builtin_bit_cast(float, u);
}

// 256 blocks x 256 threads, plain launch (1 block/CU -> co-resident).
// group g = bid&7 owns batch rows g*16..+15; col-block jb = bid>>3 owns 32 cols.
// Waves k-split the 1024-dim contraction (wave w: k in [w*256, w*256+256) as 8 k-tiles),
// LDS-reduce partials; waves 0,1 own the two 16-col output tiles (state, publish, out).
// Fence-free cross-block protocol: exchange data + flags via relaxed AGENT atomics
// (coherent via IC); __syncthreads' implied vmcnt(0) drain gives release ordering.
__global__ __launch_bounds__(256, 1) void ron_kernel(
    const float* __restrict__ x, const float* __restrict__ x2h,
    const float* __restrict__ h2h, const float* __restrict__ bias,
    const float* __restrict__ gam_, const float* __restrict__ eps_,
    float* __restrict__ out, unsigned int* __restrict__ flags,
    unsigned int* __restrict__ hy_ex) {
  const int tid = threadIdx.x;
  const int w = tid >> 6;
  const int l = tid & 63;
  const int g = blockIdx.x & 7;
  const int jb = blockIdx.x >> 3;
  const int lc = l & 15;  // A-row / output col-in-tile
  const int kg = l >> 4;  // k-subgroup / C-row group

  __shared__ f32x4 part[4][2][64];  // [wave][tile][lane] 8KB

  // ---- one-time: h2h k-slice (this wave's 8 k-tiles) x 2 col-tiles, hi/lo bf16 ----
  short8 wfh[8][2], wfl[8][2];
#pragma unroll
  for (int j = 0; j < 8; ++j) {
    const int krow = (w * 8 + j) * 32 + kg * 8;
#pragma unroll
    for (int t = 0; t < 2; ++t) {
      const int c = jb * 32 + t * 16 + lc;
#pragma unroll
      for (int jj = 0; jj < 8; ++jj) {
        float v = h2h[(size_t)(krow + jj) * NH + c];
        unsigned short hb = f2bf(v);
        wfh[j][t][jj] = (short)hb;
        wfl[j][t][jj] = (short)f2bf(v - bf2f(hb));
      }
    }
  }

  const int myc = jb * 32 + w * 16 + lc;  // owned col (waves 0,1 only)
  short8 xwh[3], xwl[3];
  float bias_c = 0.f, gam = 0.f, ep = 0.f;
  if (w < 2) {
#pragma unroll
    for (int kt = 0; kt < 3; ++kt)
#pragma unroll
      for (int jj = 0; jj < 8; ++jj) {
        float v = x2h[(size_t)(kt * 32 + kg * 8 + jj) * NH + myc];
        unsigned short hb = f2bf(v);
        xwh[kt][jj] = (short)hb;
        xwl[kt][jj] = (short)f2bf(v - bf2f(hb));
      }
    bias_c = bias[myc];
    gam = gam_[myc];
    ep = eps_[myc];
  }

  float hy[4] = {0.f, 0.f, 0.f, 0.f};
  float hz[4] = {0.f, 0.f, 0.f, 0.f};

  const float* xlane = x + (size_t)(g * 16 + lc) * LSEQ * NI + kg * 8;
  const int aoff = lc * 8 + kg * 2;  // u64 offset within an A chunk row

  unsigned int* myflag = flags + (size_t)(g * 32 + jb) * 16;       // 64B-spaced
  unsigned int* watch = flags + (size_t)(g * 32 + (l & 31)) * 16;  // lane watches producer l&31

  for (int s = 0; s < LSEQ; ++s) {
    // ---- x-projection (waves 0,1) — runs in the slack before peers' flags land ----
    f32x4 accx = {0.f, 0.f, 0.f, 0.f};
    if (w < 2) {
      const float* xs = xlane + (size_t)s * NI;
#pragma unroll
      for (int kt = 0; kt < 3; ++kt) {
        f32x4 x0 = *(const f32x4*)(xs + kt * 32);
        f32x4 x1 = *(const f32x4*)(xs + kt * 32 + 4);
        short8 axh, axl;
#pragma unroll
        for (int jj = 0; jj < 4; ++jj) {
          unsigned short hb = f2bf(x0[jj]);
          axh[jj] = (short)hb;
          axl[jj] = (short)f2bf(x0[jj] - bf2f(hb));
          unsigned short hb2 = f2bf(x1[jj]);
          axh[jj + 4] = (short)hb2;
          axl[jj + 4] = (short)f2bf(x1[jj] - bf2f(hb2));
        }
        accx = __builtin_amdgcn_mfma_f32_16x16x32_bf16(axh, xwh[kt], accx, 0, 0, 0);
        accx = __builtin_amdgcn_mfma_f32_16x16x32_bf16(axl, xwh[kt], accx, 0, 0, 0);
        accx = __builtin_amdgcn_mfma_f32_16x16x32_bf16(axh, xwl[kt], accx, 0, 0, 0);
      }
    }

    f32x4 acc0 = {0.f, 0.f, 0.f, 0.f}, acc1 = {0.f, 0.f, 0.f, 0.f};
    if (s) {
      // ---- wait for all 32 producers of this group to publish step s-1 ----
      int guard = 0;
      for (;;) {
        unsigned int v = __hip_atomic_load(watch, __ATOMIC_RELAXED, __HIP_MEMORY_SCOPE_AGENT);
        if (!__any((int)v < s)) break;
        if (++guard > (1 << 20)) break;  // anti-hang safety
        __builtin_amdgcn_s_sleep(1);
      }
      asm volatile("" ::: "memory");  // keep loads below the spin

      // ---- coherent A-fragment loads (this wave's k-quarter), then 48 MFMAs ----
      const u64* srcg = (const u64*)hy_ex + (size_t)(((s & 1) ^ 1) * 8 + g) * 8192;
      u64 ah0[8], ah1[8], al0[8], al1[8];
#pragma unroll
      for (int j = 0; j < 8; ++j) {
        const int idx = (w * 8 + j) * 128 + aoff;
        ah0[j] = __hip_atomic_load(srcg + idx, __ATOMIC_RELAXED, __HIP_MEMORY_SCOPE_AGENT);
        ah1[j] = __hip_atomic_load(srcg + idx + 1, __ATOMIC_RELAXED, __HIP_MEMORY_SCOPE_AGENT);
        al0[j] = __hip_atomic_load(srcg + 4096 + idx, __ATOMIC_RELAXED, __HIP_MEMORY_SCOPE_AGENT);
        al1[j] = __hip_atomic_load(srcg + 4096 + idx + 1, __ATOMIC_RELAXED, __HIP_MEMORY_SCOPE_AGENT);
      }
#pragma unroll
      for (int j = 0; j < 8; ++j) {
        short8 fh = __builtin_bit_cast(short8, (u64x2){ah0[j], ah1[j]});
        short8 fl = __builtin_bit_cast(short8, (u64x2){al0[j], al1[j]});
        acc0 = __builtin_amdgcn_mfma_f32_16x16x32_bf16(fh, wfh[j][0], acc0, 0, 0, 0);
        acc1 = __builtin_amdgcn_mfma_f32_16x16x32_bf16(fh, wfh[j][1], acc1, 0, 0, 0);
        acc0 = __builtin_amdgcn_mfma_f32_16x16x32_bf16(fl, wfh[j][0], acc0, 0, 0, 0);
        acc1 = __builtin_amdgcn_mfma_f32_16x16x32_bf16(fl, wfh[j][1], acc1, 0, 0, 0);
        acc0 = __builtin_amdgcn_mfma_f32_16x16x32_bf16(fh, wfl[j][0], acc0, 0, 0, 0);
        acc1 = __builtin_amdgcn_mfma_f32_16x16x32_bf16(fh, wfl[j][1], acc1, 0, 0, 0);
      }
    }

    // ---- cross-wave partial reduction via LDS ----
    part[w][0][l] = acc0;
    part[w][1][l] = acc1;
    __syncthreads();

    if (w < 2) {
      f32x4 r = accx + (w == 0 ? acc0 : acc1);
#pragma unroll
      for (int ww = 0; ww < 4; ++ww)
        if (ww != w) r += part[ww][w][l];

      unsigned int* dstg = hy_ex + (size_t)((s & 1) * 8 + g) * 16384;
      const int ktc = myc >> 5, kgc = (myc >> 3) & 3, sh = myc & 7;
#pragma unroll
      for (int i = 0; i < 4; ++i) {
        float a = r[i] + bias_c;
        float th = tanhf(a);
        hz[i] += DT * (th - gam * hy[i] - ep * hz[i]);
        hy[i] += DT * hz[i];
        const int rr = kg * 4 + i;
        unsigned short hb = f2bf(hy[i]);
        unsigned short lb = f2bf(hy[i] - bf2f(hb));
        unsigned int oh = (unsigned int)__shfl_xor((int)hb, 1, 64);
        unsigned int ol = (unsigned int)__shfl_xor((int)lb, 1, 64);
        if (!(lc & 1)) {  // even col stores the (c, c+1) pair
          const int u32idx = (ktc * 512 + rr * 32 + kgc * 8 + sh) >> 1;
          __hip_atomic_store(dstg + u32idx, (unsigned int)hb | (oh << 16),
                             __ATOMIC_RELAXED, __HIP_MEMORY_SCOPE_AGENT);
          __hip_atomic_store(dstg + 8192 + u32idx, (unsigned int)lb | (ol << 16),
                             __ATOMIC_RELAXED, __HIP_MEMORY_SCOPE_AGENT);
        }
        out[((size_t)(g * 16 + rr) * LSEQ + s) * NH + myc] = hy[i];
      }
    }

    asm volatile("" ::: "memory");
    __syncthreads();  // implied s_waitcnt vmcnt(0) drains publishes -> release
    if (tid == 0)
      __hip_atomic_store(myflag, (unsigned int)(s + 1), __ATOMIC_RELAXED,
                         __HIP_MEMORY_SCOPE_AGENT);
  }
}

extern "C" void kernel_launch(void* const* d_in, const int* in_sizes, int n_in,
                              void* d_out, int out_size, void* d_ws, size_t ws_size,
                              hipStream_t stream) {
  const float* x = (const float*)d_in[0];
  const float* x2h = (const float*)d_in[1];
  const float* h2h = (const float*)d_in[2];
  const float* bias = (const float*)d_in[3];
  const float* gam = (const float*)d_in[4];
  const float* eps = (const float*)d_in[5];
  float* out = (float*)d_out;

  unsigned int* flags = (unsigned int*)d_ws;                    // 16KB: 256 flags, 64B apart
  unsigned int* hy_ex = (unsigned int*)((char*)d_ws + 16384);   // 2 bufs x 8 groups x 64KB = 1MB

  // only flags need zeroing (step 0 never reads the exchange buffer)
  hipMemsetAsync(d_ws, 0, 16384, stream);

  ron_kernel<<<dim3(256), dim3(256), 0, stream>>>(x, x2h, h2h, bias, gam, eps, out, flags, hy_ex);
}

// Round 5
// 1873.936 us; speedup vs baseline: 12.5769x; 1.5792x over previous
//
#include <hip/hip_runtime.h>
#include <math.h>

typedef short short8 __attribute__((ext_vector_type(8)));
typedef float f32x4 __attribute__((ext_vector_type(4)));
typedef unsigned long long u64;
typedef u64 u64x2 __attribute__((ext_vector_type(2)));

#define DT 0.042f
#define LSEQ 512
#define NI 96
#define NH 1024

static __device__ __forceinline__ unsigned short f2bf(float f) {
  unsigned int u = __builtin_bit_cast(unsigned int, f);
  return (unsigned short)((u + 0x7fffu + ((u >> 16) & 1u)) >> 16);
}
static __device__ __forceinline__ float bf2f(unsigned short h) {
  unsigned int u = ((unsigned int)h) << 16;
  return __builtin_bit_cast(float, u);
}
static __device__ __forceinline__ float fast_tanhf(float a) {
  float ax = __builtin_fabsf(a);
  float e = __expf(2.0f * ax);  // overflow -> inf -> t = 1, no NaN
  float t = 1.0f - 2.0f / (e + 1.0f);
  return a < 0.0f ? -t : t;
}

// 256 blocks x 512 threads (8 waves), plain launch: 1 block/CU on 256 CUs -> co-resident.
// group g = bid&7 owns batch rows g*16..+15; col-block jb = bid>>3 owns 32 cols.
// 8 waves k-split the 1024-dim contraction: wave w handles k-tiles w*4..w*4+3.
// Per-wave producer watch (wave w waits only on its 4 k-suppliers) + TRIPLE buffering:
// a block at step s has collectively (union of its 8 waves) seen all 32 flags >= s-1,
// so every block finished reading buffer (s-3)%3 == s%3 before it is overwritten.
// All cross-block traffic via relaxed AGENT-scope atomics (proven rounds 2-3);
// __syncthreads' implicit vmcnt(0) drain before s_barrier provides release ordering.
__global__ __launch_bounds__(512, 2) void ron_kernel(
    const float* __restrict__ x, const float* __restrict__ x2h,
    const float* __restrict__ h2h, const float* __restrict__ bias,
    const float* __restrict__ gam_, const float* __restrict__ eps_,
    float* __restrict__ out, unsigned int* __restrict__ flags,
    unsigned int* __restrict__ hy_ex) {
  const int tid = threadIdx.x;
  const int w = tid >> 6;  // 0..7
  const int l = tid & 63;
  const int g = blockIdx.x & 7;
  const int jb = blockIdx.x >> 3;
  const int lc = l & 15;
  const int kg = l >> 4;

  __shared__ f32x4 part[8][2][64];  // 16KB

  // ---- one-time: h2h k-slice (wave's 4 k-tiles) x 2 col-tiles, hi/lo bf16 (64 VGPR) ----
  short8 wfh[4][2], wfl[4][2];
#pragma unroll
  for (int j = 0; j < 4; ++j) {
    const int krow = (w * 4 + j) * 32 + kg * 8;
#pragma unroll
    for (int t = 0; t < 2; ++t) {
      const int c = jb * 32 + t * 16 + lc;
#pragma unroll
      for (int jj = 0; jj < 8; ++jj) {
        float v = h2h[(size_t)(krow + jj) * NH + c];
        unsigned short hb = f2bf(v);
        wfh[j][t][jj] = (short)hb;
        wfl[j][t][jj] = (short)f2bf(v - bf2f(hb));
      }
    }
  }
  const int myc = jb * 32 + w * 16 + lc;  // owned col (waves 0,1 only)
  short8 xwh[3], xwl[3];
  float bias_c = 0.f, gam = 0.f, ep = 0.f;
  if (w < 2) {
#pragma unroll
    for (int kt = 0; kt < 3; ++kt)
#pragma unroll
      for (int jj = 0; jj < 8; ++jj) {
        float v = x2h[(size_t)(kt * 32 + kg * 8 + jj) * NH + myc];
        unsigned short hb = f2bf(v);
        xwh[kt][jj] = (short)hb;
        xwl[kt][jj] = (short)f2bf(v - bf2f(hb));
      }
    bias_c = bias[myc];
    gam = gam_[myc];
    ep = eps_[myc];
  }

  float hy[4] = {0.f, 0.f, 0.f, 0.f};
  float hz[4] = {0.f, 0.f, 0.f, 0.f};
  const float* xlane = x + (size_t)(g * 16 + lc) * LSEQ * NI + kg * 8;
  const int aoff = lc * 8 + kg * 2;  // u64 units within a 128-u64 chunk
  unsigned int* myflag = flags + (size_t)(g * 32 + jb) * 16;              // 64B-spaced
  unsigned int* watch = flags + (size_t)(g * 32 + w * 4 + (l & 3)) * 16;  // wave's 4 suppliers
  const int ktc = myc >> 5, kgc = (myc >> 3) & 3, sh = myc & 7;

  // ---- prefetch x for s=0 ----
  f32x4 xr[6];
  if (w < 2) {
    const float* xs = xlane;
#pragma unroll
    for (int kt = 0; kt < 3; ++kt) {
      xr[2 * kt] = *(const f32x4*)(xs + kt * 32);
      xr[2 * kt + 1] = *(const f32x4*)(xs + kt * 32 + 4);
    }
  }

  for (int s = 0; s < LSEQ; ++s) {
    const int wb = s % 3;                // write buffer
    const int rb = wb ? wb - 1 : 2;      // read buffer = (s-1)%3

    // ---- pack x(s) frags from prefetched regs, then issue prefetch of x(s+1) ----
    short8 axh[3], axl[3];
    if (w < 2) {
#pragma unroll
      for (int kt = 0; kt < 3; ++kt) {
#pragma unroll
        for (int jj = 0; jj < 4; ++jj) {
          unsigned short hb = f2bf(xr[2 * kt][jj]);
          axh[kt][jj] = (short)hb;
          axl[kt][jj] = (short)f2bf(xr[2 * kt][jj] - bf2f(hb));
          unsigned short hb2 = f2bf(xr[2 * kt + 1][jj]);
          axh[kt][jj + 4] = (short)hb2;
          axl[kt][jj + 4] = (short)f2bf(xr[2 * kt + 1][jj] - bf2f(hb2));
        }
      }
      const float* xs2 = xlane + (size_t)(s + 1 < LSEQ ? s + 1 : s) * NI;
#pragma unroll
      for (int kt = 0; kt < 3; ++kt) {
        xr[2 * kt] = *(const f32x4*)(xs2 + kt * 32);
        xr[2 * kt + 1] = *(const f32x4*)(xs2 + kt * 32 + 4);
      }
    }

    f32x4 a0a = {0.f, 0.f, 0.f, 0.f}, a0b = {0.f, 0.f, 0.f, 0.f};
    f32x4 a1a = {0.f, 0.f, 0.f, 0.f}, a1b = {0.f, 0.f, 0.f, 0.f};
    f32x4 accx = {0.f, 0.f, 0.f, 0.f};
    u64 ah0[4], ah1[4], al0[4], al1[4];

    if (s) {
      // ---- wait for this wave's 4 suppliers to publish step s-1 ----
      int guard = 0;
      for (;;) {
        unsigned int v = __hip_atomic_load(watch, __ATOMIC_RELAXED, __HIP_MEMORY_SCOPE_AGENT);
        if (!__any((int)v < s)) break;
        if (++guard > (1 << 18)) break;  // anti-hang safety
        __builtin_amdgcn_s_sleep(1);
      }
      asm volatile("" ::: "memory");  // keep A-loads below the spin

      // ---- issue A-fragment loads (wave's k-quarter: 16 u64) ----
      const u64* srcg = (const u64*)hy_ex + (size_t)(rb * 8 + g) * 8192;
#pragma unroll
      for (int j = 0; j < 4; ++j) {
        const int idx = (w * 4 + j) * 128 + aoff;
        ah0[j] = __hip_atomic_load(srcg + idx, __ATOMIC_RELAXED, __HIP_MEMORY_SCOPE_AGENT);
        ah1[j] = __hip_atomic_load(srcg + idx + 1, __ATOMIC_RELAXED, __HIP_MEMORY_SCOPE_AGENT);
        al0[j] = __hip_atomic_load(srcg + 4096 + idx, __ATOMIC_RELAXED, __HIP_MEMORY_SCOPE_AGENT);
        al1[j] = __hip_atomic_load(srcg + 4096 + idx + 1, __ATOMIC_RELAXED, __HIP_MEMORY_SCOPE_AGENT);
      }
    }

    // ---- x-projection MFMAs (waves 0,1): overlap the A-load round trip ----
    if (w < 2) {
#pragma unroll
      for (int kt = 0; kt < 3; ++kt) {
        accx = __builtin_amdgcn_mfma_f32_16x16x32_bf16(axh[kt], xwh[kt], accx, 0, 0, 0);
        accx = __builtin_amdgcn_mfma_f32_16x16x32_bf16(axl[kt], xwh[kt], accx, 0, 0, 0);
        accx = __builtin_amdgcn_mfma_f32_16x16x32_bf16(axh[kt], xwl[kt], accx, 0, 0, 0);
      }
    }

    if (s) {
      // ---- 24 h2h MFMAs (4 j-tiles x 6), 4 accumulator chains ----
#pragma unroll
      for (int j = 0; j < 4; ++j) {
        short8 fh = __builtin_bit_cast(short8, (u64x2){ah0[j], ah1[j]});
        short8 fl = __builtin_bit_cast(short8, (u64x2){al0[j], al1[j]});
        if (j & 1) {
          a0b = __builtin_amdgcn_mfma_f32_16x16x32_bf16(fh, wfh[j][0], a0b, 0, 0, 0);
          a1b = __builtin_amdgcn_mfma_f32_16x16x32_bf16(fh, wfh[j][1], a1b, 0, 0, 0);
          a0b = __builtin_amdgcn_mfma_f32_16x16x32_bf16(fl, wfh[j][0], a0b, 0, 0, 0);
          a1b = __builtin_amdgcn_mfma_f32_16x16x32_bf16(fl, wfh[j][1], a1b, 0, 0, 0);
          a0b = __builtin_amdgcn_mfma_f32_16x16x32_bf16(fh, wfl[j][0], a0b, 0, 0, 0);
          a1b = __builtin_amdgcn_mfma_f32_16x16x32_bf16(fh, wfl[j][1], a1b, 0, 0, 0);
        } else {
          a0a = __builtin_amdgcn_mfma_f32_16x16x32_bf16(fh, wfh[j][0], a0a, 0, 0, 0);
          a1a = __builtin_amdgcn_mfma_f32_16x16x32_bf16(fh, wfh[j][1], a1a, 0, 0, 0);
          a0a = __builtin_amdgcn_mfma_f32_16x16x32_bf16(fl, wfh[j][0], a0a, 0, 0, 0);
          a1a = __builtin_amdgcn_mfma_f32_16x16x32_bf16(fl, wfh[j][1], a1a, 0, 0, 0);
          a0a = __builtin_amdgcn_mfma_f32_16x16x32_bf16(fh, wfl[j][0], a0a, 0, 0, 0);
          a1a = __builtin_amdgcn_mfma_f32_16x16x32_bf16(fh, wfl[j][1], a1a, 0, 0, 0);
        }
      }
    }

    // ---- cross-wave k-reduction via LDS ----
    part[w][0][l] = a0a + a0b;
    part[w][1][l] = a1a + a1b;
    __syncthreads();

    if (w < 2) {
      f32x4 r = accx;
#pragma unroll
      for (int ww = 0; ww < 8; ++ww) r += part[ww][w][l];

      unsigned int* dstg = hy_ex + (size_t)(wb * 8 + g) * 16384;
#pragma unroll
      for (int i = 0; i < 4; ++i) {
        float a = r[i] + bias_c;
        float th = fast_tanhf(a);
        hz[i] += DT * (th - gam * hy[i] - ep * hz[i]);
        hy[i] += DT * hz[i];
        const int rr = kg * 4 + i;
        unsigned short hb = f2bf(hy[i]);
        unsigned short lb = f2bf(hy[i] - bf2f(hb));
        unsigned int oh = (unsigned int)__shfl_xor((int)hb, 1, 64);
        unsigned int ol = (unsigned int)__shfl_xor((int)lb, 1, 64);
        if (!(lc & 1)) {  // even col stores the (c, c+1) pair
          const int u32idx = (ktc * 512 + rr * 32 + kgc * 8 + sh) >> 1;
          __hip_atomic_store(dstg + u32idx, (unsigned int)hb | (oh << 16),
                             __ATOMIC_RELAXED, __HIP_MEMORY_SCOPE_AGENT);
          __hip_atomic_store(dstg + 8192 + u32idx, (unsigned int)lb | (ol << 16),
                             __ATOMIC_RELAXED, __HIP_MEMORY_SCOPE_AGENT);
        }
      }
    }

    asm volatile("" ::: "memory");
    __syncthreads();  // implicit vmcnt(0) drain -> publish stores at coherence point
    if (tid == 0)
      __hip_atomic_store(myflag, (unsigned int)(s + 1), __ATOMIC_RELAXED,
                         __HIP_MEMORY_SCOPE_AGENT);

    // ---- out[] stores AFTER the flag: DRAM ack off the critical path ----
    if (w < 2) {
#pragma unroll
      for (int i = 0; i < 4; ++i)
        out[((size_t)(g * 16 + kg * 4 + i) * LSEQ + s) * NH + myc] = hy[i];
    }
  }
}

extern "C" void kernel_launch(void* const* d_in, const int* in_sizes, int n_in,
                              void* d_out, int out_size, void* d_ws, size_t ws_size,
                              hipStream_t stream) {
  const float* x = (const float*)d_in[0];
  const float* x2h = (const float*)d_in[1];
  const float* h2h = (const float*)d_in[2];
  const float* bias = (const float*)d_in[3];
  const float* gam = (const float*)d_in[4];
  const float* eps = (const float*)d_in[5];
  float* out = (float*)d_out;

  unsigned int* flags = (unsigned int*)d_ws;                    // 16KB: 256 flags, 64B apart
  unsigned int* hy_ex = (unsigned int*)((char*)d_ws + 16384);   // 3 bufs x 8 groups x 64KB = 1.5MB

  // only flags need zeroing (step 0 never reads hy_ex)
  hipMemsetAsync(d_ws, 0, 16384, stream);

  ron_kernel<<<dim3(256), dim3(512), 0, stream>>>(x, x2h, h2h, bias, gam, eps, out, flags, hy_ex);
}

// Round 8
// 1796.405 us; speedup vs baseline: 13.1197x; 1.0432x over previous
//
#include <hip/hip_runtime.h>
#include <math.h>

typedef short short8 __attribute__((ext_vector_type(8)));
typedef float f32x4 __attribute__((ext_vector_type(4)));
typedef unsigned long long u64;
typedef u64 u64x2 __attribute__((ext_vector_type(2)));

#define DT 0.042f
#define LSEQ 512
#define NI 96
#define NH 1024

static __device__ __forceinline__ unsigned short f2bf(float f) {
  unsigned int u = __builtin_bit_cast(unsigned int, f);
  return (unsigned short)((u + 0x7fffu + ((u >> 16) & 1u)) >> 16);
}
static __device__ __forceinline__ float bf2f(unsigned short h) {
  unsigned int u = ((unsigned int)h) << 16;
  return __builtin_bit_cast(float, u);
}
static __device__ __forceinline__ float fast_tanhf(float a) {
  float ax = __builtin_fabsf(a);
  float e = __expf(2.0f * ax);  // overflow -> inf -> t = 1, no NaN
  float t = 1.0f - 2.0f / (e + 1.0f);
  return a < 0.0f ? -t : t;
}

// ---- DATA ops only are scope-templated. Flags ALWAYS use proven agent atomics (IC).
// F=true: sc0 (XCD-local L2) for hy_ex data — valid only for verified co-XCD groups.
template <bool F>
static __device__ __forceinline__ void ld16_issue(u64x2* dst, const u64* p) {
  if constexpr (F) {
    asm volatile("global_load_dwordx4 %0, %1, off sc0" : "=v"(*dst) : "v"(p) : "memory");
  } else {
    u64 a = __hip_atomic_load(p, __ATOMIC_RELAXED, __HIP_MEMORY_SCOPE_AGENT);
    u64 b = __hip_atomic_load(p + 1, __ATOMIC_RELAXED, __HIP_MEMORY_SCOPE_AGENT);
    *dst = (u64x2){a, b};
  }
}
template <bool F>
static __device__ __forceinline__ void ld_fence() {  // A-frags resident (rule #18)
  if constexpr (F) {
    asm volatile("s_waitcnt vmcnt(0)" ::: "memory");
    __builtin_amdgcn_sched_barrier(0);
  }
}
template <bool F>
static __device__ __forceinline__ void stpub(unsigned int* p, unsigned int v) {
  if constexpr (F)
    asm volatile("global_store_dword %0, %1, off sc0" ::"v"(p), "v"(v) : "memory");
  else
    __hip_atomic_store(p, v, __ATOMIC_RELAXED, __HIP_MEMORY_SCOPE_AGENT);
}
static __device__ __forceinline__ void drain_vm() {  // explicit: publishes committed
  asm volatile("s_waitcnt vmcnt(0)" ::: "memory");
  __builtin_amdgcn_sched_barrier(0);
}
template <bool B> struct BoolC { static constexpr bool value = B; };

// 256 blocks x 512 threads. Group g (16 batch rows) x col-block jb (32 cols); 8 waves
// k-split 1024; per-wave watch of its 4 suppliers + triple buffering (r5 invariant:
// union of the 8 waves' watch sets = all 32 producers -> buffer (s-3)%3 fully read).
// Mapping (g, jb, fast) from a table built by block 0 from ACTUAL XCD placement;
// exact-32 co-XCD sets -> fast (hy_ex data via sc0 in that XCD's L2), else slow
// (agent/IC data path, byte-proven in round 5). Flags always agent/IC (proven).
// Explicit vmcnt(0) drain before the barrier that precedes each flag post.
__global__ __launch_bounds__(512, 2) void ron_kernel(
    const float* __restrict__ x, const float* __restrict__ x2h,
    const float* __restrict__ h2h, const float* __restrict__ bias,
    const float* __restrict__ gam_, const float* __restrict__ eps_,
    float* __restrict__ out, unsigned int* __restrict__ flags,
    unsigned int* __restrict__ hy_ex) {
  const int tid = threadIdx.x;
  const int w = tid >> 6;  // 0..7
  const int l = tid & 63;
  const int lc = l & 15;
  const int kg = l >> 4;

  __shared__ f32x4 part[8][2][64];  // 16KB
  __shared__ int info_sh;

  unsigned int* base = flags + 4096;  // byte 16384
  unsigned int* xcdtab = base;        // [0..255]
  unsigned int* ctr = base + 256;
  unsigned int* abortw = base + 257;
  unsigned int* enttab = base + 272;  // [0..255]

  // ---- publish my XCD (every block) ----
  if (tid == 0) {
    unsigned int myxcd = __builtin_amdgcn_s_getreg(63508) & 15u;  // hwreg(XCC_ID=20,0,32)
    __hip_atomic_store(xcdtab + blockIdx.x, 0x100u | myxcd, __ATOMIC_RELAXED,
                       __HIP_MEMORY_SCOPE_AGENT);
    __hip_atomic_fetch_add(ctr, 1u, __ATOMIC_RELAXED, __HIP_MEMORY_SCOPE_AGENT);
  }

  // ---- block 0: build the (g, jb, mode) table — single source of truth ----
  if (blockIdx.x == 0 && tid == 0) {
    int gu = 0;
    while (__hip_atomic_load(ctr, __ATOMIC_RELAXED, __HIP_MEMORY_SCOPE_AGENT) < 256u) {
      if (++gu > (1 << 17)) break;  // ~75ms
      __builtin_amdgcn_s_sleep(8);
    }
    bool ok = (gu <= (1 << 17));
    unsigned char xs[256];
    if (ok) {
      for (int i = 0; i < 256; ++i) {
        unsigned int v = __hip_atomic_load(xcdtab + i, __ATOMIC_RELAXED, __HIP_MEMORY_SCOPE_AGENT);
        int g2 = 0;
        while (v == 0 && ++g2 <= 8192) {
          __builtin_amdgcn_s_sleep(2);
          v = __hip_atomic_load(xcdtab + i, __ATOMIC_RELAXED, __HIP_MEMORY_SCOPE_AGENT);
        }
        if (v == 0) { ok = false; break; }
        xs[i] = (unsigned char)(v & 15u);
      }
    }
    unsigned int ent[256];
    if (ok) {
      int gidx = 0, nl = 0;
      unsigned char left[256], tmp[256];
      for (unsigned int xc = 0; xc < 16u && gidx < 8; ++xc) {
        int cnt = 0;
        for (int i = 0; i < 256; ++i)
          if (xs[i] == (unsigned char)xc) tmp[cnt++] = (unsigned char)i;
        int p = 0;
        while (cnt - p >= 32 && gidx < 8) {  // exact-32 co-XCD set -> fast
          for (int k2 = 0; k2 < 32; ++k2)
            ent[tmp[p + k2]] = 1u | ((unsigned)gidx << 1) | ((unsigned)k2 << 4) | (1u << 9);
          ++gidx; p += 32;
        }
        for (; p < cnt; ++p) left[nl++] = tmp[p];
      }
      int li = 0;
      while (gidx < 8) {  // mixed leftovers -> slow (proven protocol)
        for (int k2 = 0; k2 < 32 && li < nl; ++k2, ++li)
          ent[left[li]] = 1u | ((unsigned)gidx << 1) | ((unsigned)k2 << 4);
        ++gidx;
      }
    } else {
      for (int i = 0; i < 256; ++i)
        ent[i] = 1u | ((unsigned)(i & 7) << 1) | ((unsigned)(i >> 3) << 4);
    }
    for (int i = 0; i < 256; ++i)
      __hip_atomic_store(enttab + i, ent[i], __ATOMIC_RELAXED, __HIP_MEMORY_SCOPE_AGENT);
  }

  // ---- every block: fetch my entry (long guard -> partial timeout ~impossible) ----
  if (tid == 0) {
    unsigned int e = 0;
    int gu = 0;
    for (;;) {
      e = __hip_atomic_load(enttab + blockIdx.x, __ATOMIC_RELAXED, __HIP_MEMORY_SCOPE_AGENT);
      if (e || ++gu > (1 << 17)) break;  // ~150ms
      __builtin_amdgcn_s_sleep(16);
    }
    if (!e) e = 1u | ((unsigned)(blockIdx.x & 7) << 1) | ((unsigned)(blockIdx.x >> 3) << 4);
    info_sh = (int)e;
  }
  __syncthreads();
  const unsigned int ent = (unsigned int)info_sh;
  const int g = (ent >> 1) & 7;
  const int jb = (ent >> 4) & 31;
  const bool fastm = ((ent >> 9) & 1) != 0;

  // ---- one-time: h2h k-slice (wave's 4 k-tiles) x 2 col-tiles, hi/lo bf16 ----
  short8 wfh[4][2], wfl[4][2];
#pragma unroll
  for (int j = 0; j < 4; ++j) {
    const int krow = (w * 4 + j) * 32 + kg * 8;
#pragma unroll
    for (int t = 0; t < 2; ++t) {
      const int c = jb * 32 + t * 16 + lc;
#pragma unroll
      for (int jj = 0; jj < 8; ++jj) {
        float v = h2h[(size_t)(krow + jj) * NH + c];
        unsigned short hb = f2bf(v);
        wfh[j][t][jj] = (short)hb;
        wfl[j][t][jj] = (short)f2bf(v - bf2f(hb));
      }
    }
  }
  const int myc = jb * 32 + w * 16 + lc;  // owned col (waves 0,1 only)
  short8 xwh[3], xwl[3];
  float bias_c = 0.f, gam = 0.f, ep = 0.f;
  if (w < 2) {
#pragma unroll
    for (int kt = 0; kt < 3; ++kt)
#pragma unroll
      for (int jj = 0; jj < 8; ++jj) {
        float v = x2h[(size_t)(kt * 32 + kg * 8 + jj) * NH + myc];
        unsigned short hb = f2bf(v);
        xwh[kt][jj] = (short)hb;
        xwl[kt][jj] = (short)f2bf(v - bf2f(hb));
      }
    bias_c = bias[myc];
    gam = gam_[myc];
    ep = eps_[myc];
  }

  float hy[4] = {0.f, 0.f, 0.f, 0.f};
  float hz[4] = {0.f, 0.f, 0.f, 0.f};
  const float* xlane = x + (size_t)(g * 16 + lc) * LSEQ * NI + kg * 8;
  const int aoff = lc * 8 + kg * 2;  // u64 units within a 128-u64 chunk
  unsigned int* myflag = flags + (size_t)(g * 32 + jb) * 16;              // 64B-spaced
  unsigned int* watch = flags + (size_t)(g * 32 + w * 4 + (l & 3)) * 16;  // wave's 4 suppliers
  const int ktc = myc >> 5, kgc = (myc >> 3) & 3, sh = myc & 7;

  // ---- prefetch x for s=0 ----
  f32x4 xr[6];
  if (w < 2) {
#pragma unroll
    for (int kt = 0; kt < 3; ++kt) {
      xr[2 * kt] = *(const f32x4*)(xlane + kt * 32);
      xr[2 * kt + 1] = *(const f32x4*)(xlane + kt * 32 + 4);
    }
  }

  auto run = [&](auto fc) {
    constexpr bool F = decltype(fc)::value;
    bool noSync = false;  // watchdog: trip -> never wait again (fast, visible failure)
    for (int s = 0; s < LSEQ; ++s) {
      const int wb = s % 3;            // write buffer
      const int rb = wb ? wb - 1 : 2;  // read buffer = (s-1)%3

      // ---- pack x(s) frags from prefetched regs (x(s+1) prefetch happens at iter end) ----
      short8 axh[3], axl[3];
      if (w < 2) {
#pragma unroll
        for (int kt = 0; kt < 3; ++kt) {
#pragma unroll
          for (int jj = 0; jj < 4; ++jj) {
            unsigned short hb = f2bf(xr[2 * kt][jj]);
            axh[kt][jj] = (short)hb;
            axl[kt][jj] = (short)f2bf(xr[2 * kt][jj] - bf2f(hb));
            unsigned short hb2 = f2bf(xr[2 * kt + 1][jj]);
            axh[kt][jj + 4] = (short)hb2;
            axl[kt][jj + 4] = (short)f2bf(xr[2 * kt + 1][jj] - bf2f(hb2));
          }
        }
      }

      f32x4 a0a = {0.f, 0.f, 0.f, 0.f}, a0b = {0.f, 0.f, 0.f, 0.f};
      f32x4 a1a = {0.f, 0.f, 0.f, 0.f}, a1b = {0.f, 0.f, 0.f, 0.f};
      f32x4 accx = {0.f, 0.f, 0.f, 0.f};
      u64x2 hq[4], lq[4];

      if (s) {
        // ---- wait for this wave's 4 suppliers (agent/IC flags — proven) ----
        if (!noSync) {
          int guard = 0;
          for (;;) {
            unsigned int v = __hip_atomic_load(watch, __ATOMIC_RELAXED, __HIP_MEMORY_SCOPE_AGENT);
            if (!__any((int)v < s)) break;
            if ((++guard & 255) == 0) {
              if (__hip_atomic_load(abortw, __ATOMIC_RELAXED, __HIP_MEMORY_SCOPE_AGENT) != 0u ||
                  guard > (1 << 16)) {
                __hip_atomic_store(abortw, 1u, __ATOMIC_RELAXED, __HIP_MEMORY_SCOPE_AGENT);
                noSync = true;
                break;
              }
            }
            __builtin_amdgcn_s_sleep(1);
          }
        }
        asm volatile("" ::: "memory");  // keep A-loads below the spin

        // ---- issue A-fragment loads (wave's k-quarter: 8 x 16B) ----
        const u64* srcg = (const u64*)hy_ex + (size_t)(rb * 8 + g) * 8192;
#pragma unroll
        for (int j = 0; j < 4; ++j) {
          const int idx = (w * 4 + j) * 128 + aoff;
          ld16_issue<F>(&hq[j], srcg + idx);
          ld16_issue<F>(&lq[j], srcg + 4096 + idx);
        }
      }

      // ---- x-projection MFMAs (waves 0,1): overlap the A-load round trip ----
      if (w < 2) {
#pragma unroll
        for (int kt = 0; kt < 3; ++kt) {
          accx = __builtin_amdgcn_mfma_f32_16x16x32_bf16(axh[kt], xwh[kt], accx, 0, 0, 0);
          accx = __builtin_amdgcn_mfma_f32_16x16x32_bf16(axl[kt], xwh[kt], accx, 0, 0, 0);
          accx = __builtin_amdgcn_mfma_f32_16x16x32_bf16(axh[kt], xwl[kt], accx, 0, 0, 0);
        }
      }

      if (s) {
        ld_fence<F>();  // fast: vmcnt(0) — x(s+1) was issued last iter, already complete
#pragma unroll
        for (int j = 0; j < 4; ++j) {
          short8 fh = __builtin_bit_cast(short8, hq[j]);
          short8 fl = __builtin_bit_cast(short8, lq[j]);
          if (j & 1) {
            a0b = __builtin_amdgcn_mfma_f32_16x16x32_bf16(fh, wfh[j][0], a0b, 0, 0, 0);
            a1b = __builtin_amdgcn_mfma_f32_16x16x32_bf16(fh, wfh[j][1], a1b, 0, 0, 0);
            a0b = __builtin_amdgcn_mfma_f32_16x16x32_bf16(fl, wfh[j][0], a0b, 0, 0, 0);
            a1b = __builtin_amdgcn_mfma_f32_16x16x32_bf16(fl, wfh[j][1], a1b, 0, 0, 0);
            a0b = __builtin_amdgcn_mfma_f32_16x16x32_bf16(fh, wfl[j][0], a0b, 0, 0, 0);
            a1b = __builtin_amdgcn_mfma_f32_16x16x32_bf16(fh, wfl[j][1], a1b, 0, 0, 0);
          } else {
            a0a = __builtin_amdgcn_mfma_f32_16x16x32_bf16(fh, wfh[j][0], a0a, 0, 0, 0);
            a1a = __builtin_amdgcn_mfma_f32_16x16x32_bf16(fh, wfh[j][1], a1a, 0, 0, 0);
            a0a = __builtin_amdgcn_mfma_f32_16x16x32_bf16(fl, wfh[j][0], a0a, 0, 0, 0);
            a1a = __builtin_amdgcn_mfma_f32_16x16x32_bf16(fl, wfh[j][1], a1a, 0, 0, 0);
            a0a = __builtin_amdgcn_mfma_f32_16x16x32_bf16(fh, wfl[j][0], a0a, 0, 0, 0);
            a1a = __builtin_amdgcn_mfma_f32_16x16x32_bf16(fh, wfl[j][1], a1a, 0, 0, 0);
          }
        }
      }

      // ---- cross-wave k-reduction via LDS ----
      part[w][0][l] = a0a + a0b;
      part[w][1][l] = a1a + a1b;
      __syncthreads();

      if (w < 2) {
        f32x4 r = accx;
#pragma unroll
        for (int ww = 0; ww < 8; ++ww) r += part[ww][w][l];

        unsigned int* dstg = hy_ex + (size_t)(wb * 8 + g) * 16384;
#pragma unroll
        for (int i = 0; i < 4; ++i) {
          float a = r[i] + bias_c;
          float th = fast_tanhf(a);
          hz[i] += DT * (th - gam * hy[i] - ep * hz[i]);
          hy[i] += DT * hz[i];
          const int rr = kg * 4 + i;
          unsigned short hb = f2bf(hy[i]);
          unsigned short lb = f2bf(hy[i] - bf2f(hb));
          unsigned int oh = (unsigned int)__shfl_xor((int)hb, 1, 64);
          unsigned int ol = (unsigned int)__shfl_xor((int)lb, 1, 64);
          if (!(lc & 1)) {  // even col stores the (c, c+1) pair
            const int u32idx = (ktc * 512 + rr * 32 + kgc * 8 + sh) >> 1;
            stpub<F>(dstg + u32idx, (unsigned int)hb | (oh << 16));
            stpub<F>(dstg + 8192 + u32idx, (unsigned int)lb | (ol << 16));
          }
        }
      }

      drain_vm();       // EXPLICIT: publish stores committed before anyone posts the flag
      __syncthreads();  // all 8 waves drained
      if (tid == 0)
        __hip_atomic_store(myflag, (unsigned int)(s + 1), __ATOMIC_RELAXED,
                           __HIP_MEMORY_SCOPE_AGENT);

      // ---- off the critical path: out[] stores, then x(s+1) prefetch ----
      if (w < 2) {
#pragma unroll
        for (int i = 0; i < 4; ++i)
          out[((size_t)(g * 16 + kg * 4 + i) * LSEQ + s) * NH + myc] = hy[i];
        const float* xs2 = xlane + (size_t)(s + 1 < LSEQ ? s + 1 : s) * NI;
#pragma unroll
        for (int kt = 0; kt < 3; ++kt) {
          xr[2 * kt] = *(const f32x4*)(xs2 + kt * 32);
          xr[2 * kt + 1] = *(const f32x4*)(xs2 + kt * 32 + 4);
        }
      }
    }
  };

  if (fastm)
    run(BoolC<true>{});
  else
    run(BoolC<false>{});
}

extern "C" void kernel_launch(void* const* d_in, const int* in_sizes, int n_in,
                              void* d_out, int out_size, void* d_ws, size_t ws_size,
                              hipStream_t stream) {
  const float* x = (const float*)d_in[0];
  const float* x2h = (const float*)d_in[1];
  const float* h2h = (const float*)d_in[2];
  const float* bias = (const float*)d_in[3];
  const float* gam = (const float*)d_in[4];
  const float* eps = (const float*)d_in[5];
  float* out = (float*)d_out;

  unsigned int* flags = (unsigned int*)d_ws;                   // 16KB flags + discovery/table
  unsigned int* hy_ex = (unsigned int*)((char*)d_ws + 32768);  // 3 bufs x 8 groups x 64KB

  // zero flags + discovery + mapping table every call (step 0 never reads hy_ex)
  hipMemsetAsync(d_ws, 0, 32768, stream);

  ron_kernel<<<dim3(256), dim3(512), 0, stream>>>(x, x2h, h2h, bias, gam, eps, out, flags, hy_ex);
}